// Round 16
// baseline (175.475 us; speedup 1.0000x reference)
//
#include <hip/hip_runtime.h>

#define BATCH 8
#define NN 10000      // nodes per graph (N)
#define STB 512       // scatter2 block size
#define STB1 1024     // scatter1 (fused prep) block size

typedef _Float16 h2 __attribute__((ext_vector_type(2)));

// Packed 2xf16 LDS atomic add (ds_pk_add_f16): one atomic covers TWO batches.
__device__ __forceinline__ void lds_pk_add(h2* p, h2 v) {
    __builtin_amdgcn_ds_atomic_fadd_v2f16(
        (__attribute__((address_space(3))) h2*)p, v);
}

// ---------------- scatter 1 (prep fused, R7-style LDS staging) ----------------
// block (chunk k, batch-pair bp): stage fx=tanh(values) for (2bp,2bp+1) into
// LDS once (10000 tanh/block), per edge: 1 ds_read + 1 pk-atomic.
__global__ __launch_bounds__(STB1, 8) void scatter1_kernel(
        const float* __restrict__ values,
        const float* __restrict__ w,
        const int* __restrict__ idx,
        h2* __restrict__ partial,
        int E, int N, int chunk)
{
    __shared__ alignas(16) h2 acc2[NN];
    __shared__ alignas(16) h2 stage[NN];
    const int k = blockIdx.x, bp = blockIdx.y;
    const float* __restrict__ v0 = values + (long)(2 * bp) * N;
    const float* __restrict__ v1 = v0 + N;

    int n4 = N >> 2;                       // N % 4 == 0
    int4* az = (int4*)acc2;
    for (int i = threadIdx.x; i < n4; i += STB1) az[i] = make_int4(0, 0, 0, 0);
    for (int i = threadIdx.x; i < N; i += STB1) {
        h2 f = { (_Float16)tanhf(v0[i]), (_Float16)tanhf(v1[i]) };
        stage[i] = f;
    }
    __syncthreads();

    long e0 = (long)k * chunk, e1 = e0 + chunk;
    if (e0 > E) e0 = E;
    if (e1 > E) e1 = E;
    long n = e1 - e0;
    long nv8 = n >> 3;
    const int4*   g4p = (const int4*)(idx + e0);            // src: gather
    const int4*   s4p = (const int4*)(idx + (long)E + e0);  // tgt: scatter
    const float4* w4p = (const float4*)(w + e0);

    for (long v = threadIdx.x; v < nv8; v += STB1) {
        int4 giA = g4p[2 * v], giB = g4p[2 * v + 1];
        int4 siA = s4p[2 * v], siB = s4p[2 * v + 1];
        float4 wvA = w4p[2 * v], wvB = w4p[2 * v + 1];
        h2 fA0 = stage[giA.x], fA1 = stage[giA.y];
        h2 fA2 = stage[giA.z], fA3 = stage[giA.w];
        h2 fB0 = stage[giB.x], fB1 = stage[giB.y];
        h2 fB2 = stage[giB.z], fB3 = stage[giB.w];
        h2 wA0 = { (_Float16)wvA.x, (_Float16)wvA.x };
        h2 wA1 = { (_Float16)wvA.y, (_Float16)wvA.y };
        h2 wA2 = { (_Float16)wvA.z, (_Float16)wvA.z };
        h2 wA3 = { (_Float16)wvA.w, (_Float16)wvA.w };
        h2 wB0 = { (_Float16)wvB.x, (_Float16)wvB.x };
        h2 wB1 = { (_Float16)wvB.y, (_Float16)wvB.y };
        h2 wB2 = { (_Float16)wvB.z, (_Float16)wvB.z };
        h2 wB3 = { (_Float16)wvB.w, (_Float16)wvB.w };
        lds_pk_add(&acc2[siA.x], wA0 * fA0);
        lds_pk_add(&acc2[siA.y], wA1 * fA1);
        lds_pk_add(&acc2[siA.z], wA2 * fA2);
        lds_pk_add(&acc2[siA.w], wA3 * fA3);
        lds_pk_add(&acc2[siB.x], wB0 * fB0);
        lds_pk_add(&acc2[siB.y], wB1 * fB1);
        lds_pk_add(&acc2[siB.z], wB2 * fB2);
        lds_pk_add(&acc2[siB.w], wB3 * fB3);
    }
    for (long e = (nv8 << 3) + threadIdx.x; e < n; e += STB1) {
        int gi = idx[e0 + e], si = idx[(long)E + e0 + e];
        _Float16 wf = (_Float16)w[e0 + e];
        h2 wb = { wf, wf };
        lds_pk_add(&acc2[si], wb * stage[gi]);
    }
    __syncthreads();

    int4* pz = (int4*)(partial + ((long)k * 4 + bp) * N);
    for (int i = threadIdx.x; i < n4; i += STB1) pz[i] = az[i];
}

// ---------------- scatter 2 (VMEM h2 gather from err2) ----------------
__global__ __launch_bounds__(STB, 8) void scatter2_kernel(
        const h2* __restrict__ g2,       // [4*N] packed err
        const float* __restrict__ w,
        const int* __restrict__ idx,
        h2* __restrict__ partial,
        int E, int N, int chunk)
{
    __shared__ alignas(16) h2 acc2[NN];
    const int k = blockIdx.x, bp = blockIdx.y;
    const h2* __restrict__ gb = g2 + (long)bp * N;

    int n4 = N >> 2;
    int4* az = (int4*)acc2;
    for (int i = threadIdx.x; i < n4; i += STB) az[i] = make_int4(0, 0, 0, 0);
    __syncthreads();

    long e0 = (long)k * chunk, e1 = e0 + chunk;
    if (e0 > E) e0 = E;
    if (e1 > E) e1 = E;
    long n = e1 - e0;
    long nv8 = n >> 3;
    const int4*   g4p = (const int4*)(idx + (long)E + e0);  // tgt: gather
    const int4*   s4p = (const int4*)(idx + e0);            // src: scatter
    const float4* w4p = (const float4*)(w + e0);

    for (long v = threadIdx.x; v < nv8; v += STB) {
        int4 giA = g4p[2 * v], giB = g4p[2 * v + 1];
        int4 siA = s4p[2 * v], siB = s4p[2 * v + 1];
        float4 wvA = w4p[2 * v], wvB = w4p[2 * v + 1];
        h2 fA0 = gb[giA.x], fA1 = gb[giA.y], fA2 = gb[giA.z], fA3 = gb[giA.w];
        h2 fB0 = gb[giB.x], fB1 = gb[giB.y], fB2 = gb[giB.z], fB3 = gb[giB.w];
        h2 wA0 = { (_Float16)wvA.x, (_Float16)wvA.x };
        h2 wA1 = { (_Float16)wvA.y, (_Float16)wvA.y };
        h2 wA2 = { (_Float16)wvA.z, (_Float16)wvA.z };
        h2 wA3 = { (_Float16)wvA.w, (_Float16)wvA.w };
        h2 wB0 = { (_Float16)wvB.x, (_Float16)wvB.x };
        h2 wB1 = { (_Float16)wvB.y, (_Float16)wvB.y };
        h2 wB2 = { (_Float16)wvB.z, (_Float16)wvB.z };
        h2 wB3 = { (_Float16)wvB.w, (_Float16)wvB.w };
        lds_pk_add(&acc2[siA.x], wA0 * fA0);
        lds_pk_add(&acc2[siA.y], wA1 * fA1);
        lds_pk_add(&acc2[siA.z], wA2 * fA2);
        lds_pk_add(&acc2[siA.w], wA3 * fA3);
        lds_pk_add(&acc2[siB.x], wB0 * fB0);
        lds_pk_add(&acc2[siB.y], wB1 * fB1);
        lds_pk_add(&acc2[siB.z], wB2 * fB2);
        lds_pk_add(&acc2[siB.w], wB3 * fB3);
    }
    for (long e = (nv8 << 3) + threadIdx.x; e < n; e += STB) {
        int gi = idx[(long)E + e0 + e], si = idx[e0 + e];
        _Float16 wf = (_Float16)w[e0 + e];
        h2 wb = { wf, wf };
        lds_pk_add(&acc2[si], wb * gb[gi]);
    }
    __syncthreads();

    int4* pz = (int4*)(partial + ((long)k * 4 + bp) * N);
    for (int i = threadIdx.x; i < n4; i += STB) pz[i] = az[i];
}

// ---------------- reduce 1: pred, err, err2 ----------------
__global__ __launch_bounds__(512) void reduce1_kernel(
        const h2* __restrict__ partial,
        const float* __restrict__ values,
        float* __restrict__ pred, float* __restrict__ err,
        h2* __restrict__ err2, int N, int K)
{
    __shared__ float2 sm[16][32][4];
    const int l = threadIdx.x & 31, g = threadIdx.x >> 5;
    const int bp = blockIdx.y;
    const int t = blockIdx.x * 128 + l * 4;
    float2 a0 = {0.f,0.f}, a1 = {0.f,0.f}, a2 = {0.f,0.f}, a3 = {0.f,0.f};
    const bool ok = (t + 3) < N;
    if (ok) {
        for (int kk = g; kk < K; kk += 16) {
            int4 v = *(const int4*)(partial + (long)(kk * 4 + bp) * N + t);
            h2* hp = (h2*)&v;
            a0.x += (float)hp[0].x; a0.y += (float)hp[0].y;
            a1.x += (float)hp[1].x; a1.y += (float)hp[1].y;
            a2.x += (float)hp[2].x; a2.y += (float)hp[2].y;
            a3.x += (float)hp[3].x; a3.y += (float)hp[3].y;
        }
    }
    sm[g][l][0] = a0; sm[g][l][1] = a1; sm[g][l][2] = a2; sm[g][l][3] = a3;
    __syncthreads();
    if (g == 0 && ok) {
#pragma unroll
        for (int r = 1; r < 16; ++r) {
            a0.x += sm[r][l][0].x; a0.y += sm[r][l][0].y;
            a1.x += sm[r][l][1].x; a1.y += sm[r][l][1].y;
            a2.x += sm[r][l][2].x; a2.y += sm[r][l][2].y;
            a3.x += sm[r][l][3].x; a3.y += sm[r][l][3].y;
        }
        long j0 = (long)(2 * bp) * N + t, j1 = j0 + N;
        float4 p0 = { a0.x, a1.x, a2.x, a3.x };
        float4 p1 = { a0.y, a1.y, a2.y, a3.y };
        float4 v0 = *(const float4*)(values + j0);
        float4 v1 = *(const float4*)(values + j1);
        float4 e0 = { v0.x - p0.x, v0.y - p0.y, v0.z - p0.z, v0.w - p0.w };
        float4 e1 = { v1.x - p1.x, v1.y - p1.y, v1.z - p1.z, v1.w - p1.w };
        *(float4*)(pred + j0) = p0;
        *(float4*)(pred + j1) = p1;
        *(float4*)(err + j0) = e0;
        *(float4*)(err + j1) = e1;
        h2 pk[4] = { { (_Float16)e0.x, (_Float16)e1.x },
                     { (_Float16)e0.y, (_Float16)e1.y },
                     { (_Float16)e0.z, (_Float16)e1.z },
                     { (_Float16)e0.w, (_Float16)e1.w } };
        *(int4*)(err2 + (long)bp * N + t) = *(int4*)pk;
    }
}

// ---------------- reduce 2: dx = err - (1 - tanh^2(x)) * aggr ----------------
__global__ __launch_bounds__(512) void reduce2_kernel(
        const h2* __restrict__ partial,
        const float* __restrict__ values,
        const float* __restrict__ err,
        float* __restrict__ dx, int N, int K)
{
    __shared__ float2 sm[16][32][4];
    const int l = threadIdx.x & 31, g = threadIdx.x >> 5;
    const int bp = blockIdx.y;
    const int t = blockIdx.x * 128 + l * 4;
    float2 a0 = {0.f,0.f}, a1 = {0.f,0.f}, a2 = {0.f,0.f}, a3 = {0.f,0.f};
    const bool ok = (t + 3) < N;
    if (ok) {
        for (int kk = g; kk < K; kk += 16) {
            int4 v = *(const int4*)(partial + (long)(kk * 4 + bp) * N + t);
            h2* hp = (h2*)&v;
            a0.x += (float)hp[0].x; a0.y += (float)hp[0].y;
            a1.x += (float)hp[1].x; a1.y += (float)hp[1].y;
            a2.x += (float)hp[2].x; a2.y += (float)hp[2].y;
            a3.x += (float)hp[3].x; a3.y += (float)hp[3].y;
        }
    }
    sm[g][l][0] = a0; sm[g][l][1] = a1; sm[g][l][2] = a2; sm[g][l][3] = a3;
    __syncthreads();
    if (g == 0 && ok) {
#pragma unroll
        for (int r = 1; r < 16; ++r) {
            a0.x += sm[r][l][0].x; a0.y += sm[r][l][0].y;
            a1.x += sm[r][l][1].x; a1.y += sm[r][l][1].y;
            a2.x += sm[r][l][2].x; a2.y += sm[r][l][2].y;
            a3.x += sm[r][l][3].x; a3.y += sm[r][l][3].y;
        }
        long j0 = (long)(2 * bp) * N + t, j1 = j0 + N;
        float4 g0 = { a0.x, a1.x, a2.x, a3.x };
        float4 g1 = { a0.y, a1.y, a2.y, a3.y };
        float4 v0 = *(const float4*)(values + j0);
        float4 v1 = *(const float4*)(values + j1);
        float4 e0 = *(const float4*)(err + j0);
        float4 e1 = *(const float4*)(err + j1);
        float4 d0, d1;
        float f;
        f = tanhf(v0.x); d0.x = e0.x - (1.0f - f * f) * g0.x;
        f = tanhf(v0.y); d0.y = e0.y - (1.0f - f * f) * g0.y;
        f = tanhf(v0.z); d0.z = e0.z - (1.0f - f * f) * g0.z;
        f = tanhf(v0.w); d0.w = e0.w - (1.0f - f * f) * g0.w;
        f = tanhf(v1.x); d1.x = e1.x - (1.0f - f * f) * g1.x;
        f = tanhf(v1.y); d1.y = e1.y - (1.0f - f * f) * g1.y;
        f = tanhf(v1.z); d1.z = e1.z - (1.0f - f * f) * g1.z;
        f = tanhf(v1.w); d1.w = e1.w - (1.0f - f * f) * g1.w;
        *(float4*)(dx + j0) = d0;
        *(float4*)(dx + j1) = d1;
    }
}

extern "C" void kernel_launch(void* const* d_in, const int* in_sizes, int n_in,
                              void* d_out, int out_size, void* d_ws, size_t ws_size,
                              hipStream_t stream) {
    const float* values  = (const float*)d_in[0];   // [B*N]
    const float* weights = (const float*)d_in[1];   // [E]
    const int*   edge_ix = (const int*)d_in[2];     // [2, E]

    const int BN = in_sizes[0];        // 80000
    const int E  = in_sizes[1];        // 2,000,000
    const int N  = BN / BATCH;         // 10000

    float* out  = (float*)d_out;       // [3, B*N]
    float* pred = out;
    float* err  = out + BN;
    float* dx   = out + 2 * BN;

    // workspace: err2 [4N] h2 | partial [K*4][N] h2
    auto align16 = [](size_t x) { return (x + 15) & ~(size_t)15; };
    char* ws = (char*)d_ws;
    h2* err2 = (h2*)ws;
    size_t off = align16((size_t)4 * N * sizeof(h2));
    int K = 64;   // sgrid 256 blocks = 1/CU, partial matrix 10.25 MB
    while (K > 16 && off + (size_t)K * 4 * N * sizeof(h2) > ws_size) K >>= 1;
    h2* partial = (h2*)(ws + off);

    int chunk = (((E + K - 1) / K) + 7) & ~7;   // multiple of 8
    int Kused = (E + chunk - 1) / chunk;

    dim3 sgrid(Kused, 4);                 // 4 batch-pairs
    dim3 rgrid((N + 127) / 128, 4);       // 316 reduce blocks

    scatter1_kernel<<<sgrid, STB1, 0, stream>>>(values, weights, edge_ix,
                                                partial, E, N, chunk);
    reduce1_kernel<<<rgrid, 512, 0, stream>>>(partial, values, pred, err,
                                              err2, N, Kused);
    scatter2_kernel<<<sgrid, STB, 0, stream>>>(err2, weights, edge_ix, partial,
                                               E, N, chunk);
    reduce2_kernel<<<rgrid, 512, 0, stream>>>(partial, values, err, dx,
                                              N, Kused);
}

// Round 17
// 170.656 us; speedup vs baseline: 1.0282x; 1.0282x over previous
//
#include <hip/hip_runtime.h>

#define BATCH 8
#define NN 10000      // nodes per graph (N)
#define STB 512       // scatter block size (40KB LDS -> 4 blocks/CU capacity)

typedef _Float16 h2 __attribute__((ext_vector_type(2)));

// Packed 2xf16 LDS atomic add (ds_pk_add_f16): one atomic covers TWO batches.
__device__ __forceinline__ void lds_pk_add(h2* p, h2 v) {
    __builtin_amdgcn_ds_atomic_fadd_v2f16(
        (__attribute__((address_space(3))) h2*)p, v);
}

// prep: fx2[bp*N + t] = { tanh(values[2bp*N+t]), tanh(values[(2bp+1)*N+t]) }
__global__ __launch_bounds__(256) void prep_kernel(
        const float* __restrict__ values, h2* __restrict__ fx2, int N)
{
    int i = blockIdx.x * 256 + threadIdx.x;
    if (i >= 4 * N) return;
    int bp = i / N, t = i - bp * N;
    float a = values[(long)(2 * bp) * N + t];
    float b = values[(long)(2 * bp + 1) * N + t];
    h2 f = { (_Float16)tanhf(a), (_Float16)tanhf(b) };
    fx2[i] = f;
}

// Scatter: block (chunk k, batch-pair bp). Gather g2[bp*N + gi] (4B global,
// L1/L2-resident, VMEM pipe); pk-atomic into h2 LDS accumulator (DS pipe
// carries ONLY atomics — ~3.6 cyc/lane-visit law). 8 edges/iter for MLP.
__global__ __launch_bounds__(STB, 8) void scatter_kernel(
        const h2* __restrict__ g2,       // [4*N] packed gather values
        const float* __restrict__ w,     // [E]
        const int* __restrict__ idx,     // [2,E]
        h2* __restrict__ partial,
        int E, int N, int chunk, long goff, long soff)
{
    __shared__ alignas(16) h2 acc2[NN];
    const int k = blockIdx.x, bp = blockIdx.y;
    const h2* __restrict__ gb = g2 + (long)bp * N;

    int n4 = N >> 2;                       // N % 4 == 0
    int4* az = (int4*)acc2;
    for (int i = threadIdx.x; i < n4; i += STB) az[i] = make_int4(0, 0, 0, 0);
    __syncthreads();

    long e0 = (long)k * chunk, e1 = e0 + chunk;
    if (e0 > E) e0 = E;
    if (e1 > E) e1 = E;
    long n = e1 - e0;
    long nv8 = n >> 3;                     // 8-edge groups
    const int4*   g4p = (const int4*)(idx + goff + e0);
    const int4*   s4p = (const int4*)(idx + soff + e0);
    const float4* w4p = (const float4*)(w + e0);

    for (long v = threadIdx.x; v < nv8; v += STB) {
        int4 giA = g4p[2 * v], giB = g4p[2 * v + 1];
        int4 siA = s4p[2 * v], siB = s4p[2 * v + 1];
        float4 wvA = w4p[2 * v], wvB = w4p[2 * v + 1];
        // 8 independent VMEM gathers in flight
        h2 fA0 = gb[giA.x], fA1 = gb[giA.y], fA2 = gb[giA.z], fA3 = gb[giA.w];
        h2 fB0 = gb[giB.x], fB1 = gb[giB.y], fB2 = gb[giB.z], fB3 = gb[giB.w];
        h2 wA0 = { (_Float16)wvA.x, (_Float16)wvA.x };
        h2 wA1 = { (_Float16)wvA.y, (_Float16)wvA.y };
        h2 wA2 = { (_Float16)wvA.z, (_Float16)wvA.z };
        h2 wA3 = { (_Float16)wvA.w, (_Float16)wvA.w };
        h2 wB0 = { (_Float16)wvB.x, (_Float16)wvB.x };
        h2 wB1 = { (_Float16)wvB.y, (_Float16)wvB.y };
        h2 wB2 = { (_Float16)wvB.z, (_Float16)wvB.z };
        h2 wB3 = { (_Float16)wvB.w, (_Float16)wvB.w };
        lds_pk_add(&acc2[siA.x], wA0 * fA0);
        lds_pk_add(&acc2[siA.y], wA1 * fA1);
        lds_pk_add(&acc2[siA.z], wA2 * fA2);
        lds_pk_add(&acc2[siA.w], wA3 * fA3);
        lds_pk_add(&acc2[siB.x], wB0 * fB0);
        lds_pk_add(&acc2[siB.y], wB1 * fB1);
        lds_pk_add(&acc2[siB.z], wB2 * fB2);
        lds_pk_add(&acc2[siB.w], wB3 * fB3);
    }
    for (long e = (nv8 << 3) + threadIdx.x; e < n; e += STB) {
        int gi = idx[goff + e0 + e], si = idx[soff + e0 + e];
        _Float16 wf = (_Float16)w[e0 + e];
        h2 wb = { wf, wf };
        lds_pk_add(&acc2[si], wb * gb[gi]);
    }
    __syncthreads();

    int4* pz = (int4*)(partial + ((long)k * 4 + bp) * N);
    for (int i = threadIdx.x; i < n4; i += STB) pz[i] = az[i];
}

// ---------------- reduce 1: pred, err, err2 ----------------
// 628 blocks (t-tile 64 x 4 bp), 512 thr: 16 lanes (int4 over 4 t) x 32
// k-groups x 2 loads; log2 cross-group tree (all threads active).
__global__ __launch_bounds__(512) void reduce1_kernel(
        const h2* __restrict__ partial,
        const float* __restrict__ values,
        float* __restrict__ pred, float* __restrict__ err,
        h2* __restrict__ err2, int N, int K)
{
    __shared__ float2 sm[32][16][4];
    const int l = threadIdx.x & 15, g = threadIdx.x >> 4;
    const int bp = blockIdx.y;
    const int t = blockIdx.x * 64 + l * 4;
    float2 a0 = {0.f,0.f}, a1 = {0.f,0.f}, a2 = {0.f,0.f}, a3 = {0.f,0.f};
    const bool ok = (t + 3) < N;
    if (ok) {
        for (int kk = g; kk < K; kk += 32) {
            int4 v = *(const int4*)(partial + (long)(kk * 4 + bp) * N + t);
            h2* hp = (h2*)&v;
            a0.x += (float)hp[0].x; a0.y += (float)hp[0].y;
            a1.x += (float)hp[1].x; a1.y += (float)hp[1].y;
            a2.x += (float)hp[2].x; a2.y += (float)hp[2].y;
            a3.x += (float)hp[3].x; a3.y += (float)hp[3].y;
        }
    }
    sm[g][l][0] = a0; sm[g][l][1] = a1; sm[g][l][2] = a2; sm[g][l][3] = a3;
    __syncthreads();
#pragma unroll
    for (int s = 16; s > 0; s >>= 1) {
        if (g < s) {
#pragma unroll
            for (int j = 0; j < 4; ++j) {
                float2 o = sm[g + s][l][j];
                sm[g][l][j].x += o.x;
                sm[g][l][j].y += o.y;
            }
        }
        __syncthreads();
    }
    if (g == 0 && ok) {
        float2 b0 = sm[0][l][0], b1 = sm[0][l][1];
        float2 b2 = sm[0][l][2], b3 = sm[0][l][3];
        long j0 = (long)(2 * bp) * N + t, j1 = j0 + N;
        float4 p0 = { b0.x, b1.x, b2.x, b3.x };
        float4 p1 = { b0.y, b1.y, b2.y, b3.y };
        float4 v0 = *(const float4*)(values + j0);
        float4 v1 = *(const float4*)(values + j1);
        float4 e0 = { v0.x - p0.x, v0.y - p0.y, v0.z - p0.z, v0.w - p0.w };
        float4 e1 = { v1.x - p1.x, v1.y - p1.y, v1.z - p1.z, v1.w - p1.w };
        *(float4*)(pred + j0) = p0;
        *(float4*)(pred + j1) = p1;
        *(float4*)(err + j0) = e0;
        *(float4*)(err + j1) = e1;
        h2 pk[4] = { { (_Float16)e0.x, (_Float16)e1.x },
                     { (_Float16)e0.y, (_Float16)e1.y },
                     { (_Float16)e0.z, (_Float16)e1.z },
                     { (_Float16)e0.w, (_Float16)e1.w } };
        *(int4*)(err2 + (long)bp * N + t) = *(int4*)pk;
    }
}

// ---------------- reduce 2: dx = err - (1 - tanh^2(x)) * aggr ----------------
__global__ __launch_bounds__(512) void reduce2_kernel(
        const h2* __restrict__ partial,
        const float* __restrict__ values,
        const float* __restrict__ err,
        float* __restrict__ dx, int N, int K)
{
    __shared__ float2 sm[32][16][4];
    const int l = threadIdx.x & 15, g = threadIdx.x >> 4;
    const int bp = blockIdx.y;
    const int t = blockIdx.x * 64 + l * 4;
    float2 a0 = {0.f,0.f}, a1 = {0.f,0.f}, a2 = {0.f,0.f}, a3 = {0.f,0.f};
    const bool ok = (t + 3) < N;
    if (ok) {
        for (int kk = g; kk < K; kk += 32) {
            int4 v = *(const int4*)(partial + (long)(kk * 4 + bp) * N + t);
            h2* hp = (h2*)&v;
            a0.x += (float)hp[0].x; a0.y += (float)hp[0].y;
            a1.x += (float)hp[1].x; a1.y += (float)hp[1].y;
            a2.x += (float)hp[2].x; a2.y += (float)hp[2].y;
            a3.x += (float)hp[3].x; a3.y += (float)hp[3].y;
        }
    }
    sm[g][l][0] = a0; sm[g][l][1] = a1; sm[g][l][2] = a2; sm[g][l][3] = a3;
    __syncthreads();
#pragma unroll
    for (int s = 16; s > 0; s >>= 1) {
        if (g < s) {
#pragma unroll
            for (int j = 0; j < 4; ++j) {
                float2 o = sm[g + s][l][j];
                sm[g][l][j].x += o.x;
                sm[g][l][j].y += o.y;
            }
        }
        __syncthreads();
    }
    if (g == 0 && ok) {
        float2 b0 = sm[0][l][0], b1 = sm[0][l][1];
        float2 b2 = sm[0][l][2], b3 = sm[0][l][3];
        long j0 = (long)(2 * bp) * N + t, j1 = j0 + N;
        float4 g0 = { b0.x, b1.x, b2.x, b3.x };
        float4 g1 = { b0.y, b1.y, b2.y, b3.y };
        float4 v0 = *(const float4*)(values + j0);
        float4 v1 = *(const float4*)(values + j1);
        float4 e0 = *(const float4*)(err + j0);
        float4 e1 = *(const float4*)(err + j1);
        float4 d0, d1;
        float f;
        f = tanhf(v0.x); d0.x = e0.x - (1.0f - f * f) * g0.x;
        f = tanhf(v0.y); d0.y = e0.y - (1.0f - f * f) * g0.y;
        f = tanhf(v0.z); d0.z = e0.z - (1.0f - f * f) * g0.z;
        f = tanhf(v0.w); d0.w = e0.w - (1.0f - f * f) * g0.w;
        f = tanhf(v1.x); d1.x = e1.x - (1.0f - f * f) * g1.x;
        f = tanhf(v1.y); d1.y = e1.y - (1.0f - f * f) * g1.y;
        f = tanhf(v1.z); d1.z = e1.z - (1.0f - f * f) * g1.z;
        f = tanhf(v1.w); d1.w = e1.w - (1.0f - f * f) * g1.w;
        *(float4*)(dx + j0) = d0;
        *(float4*)(dx + j1) = d1;
    }
}

extern "C" void kernel_launch(void* const* d_in, const int* in_sizes, int n_in,
                              void* d_out, int out_size, void* d_ws, size_t ws_size,
                              hipStream_t stream) {
    const float* values  = (const float*)d_in[0];   // [B*N]
    const float* weights = (const float*)d_in[1];   // [E]
    const int*   edge_ix = (const int*)d_in[2];     // [2, E]

    const int BN = in_sizes[0];        // 80000
    const int E  = in_sizes[1];        // 2,000,000
    const int N  = BN / BATCH;         // 10000

    float* out  = (float*)d_out;       // [3, B*N]
    float* pred = out;
    float* err  = out + BN;
    float* dx   = out + 2 * BN;

    // workspace: fx2 [4N] h2 | err2 [4N] h2 | partial [K*4][N] h2
    auto align16 = [](size_t x) { return (x + 15) & ~(size_t)15; };
    char* ws = (char*)d_ws;
    h2* fx2 = (h2*)ws;
    size_t off = align16((size_t)4 * N * sizeof(h2));
    h2* err2 = (h2*)(ws + off);
    off += align16((size_t)4 * N * sizeof(h2));
    // K=64 -> sgrid 256 blocks = 1/CU (balanced), partial matrix 10.25 MB
    int K = 64;
    while (K > 16 && off + (size_t)K * 4 * N * sizeof(h2) > ws_size) K >>= 1;
    h2* partial = (h2*)(ws + off);

    int chunk = (((E + K - 1) / K) + 7) & ~7;   // multiple of 8
    int Kused = (E + chunk - 1) / chunk;

    dim3 sgrid(Kused, 4);                 // 4 batch-pairs
    dim3 rgrid((N + 63) / 64, 4);         // 628 reduce blocks (2.45/CU)

    prep_kernel<<<(4 * N + 255) / 256, 256, 0, stream>>>(values, fx2, N);
    scatter_kernel<<<sgrid, STB, 0, stream>>>(fx2, weights, edge_ix, partial,
                                              E, N, chunk, 0L, (long)E);
    reduce1_kernel<<<rgrid, 512, 0, stream>>>(partial, values, pred, err,
                                              err2, N, Kused);
    scatter_kernel<<<sgrid, STB, 0, stream>>>(err2, weights, edge_ix, partial,
                                              E, N, chunk, (long)E, 0L);
    reduce2_kernel<<<rgrid, 512, 0, stream>>>(partial, values, err, dx,
                                              N, Kused);
}